// Round 1
// baseline (140.109 us; speedup 1.0000x reference)
//
#include <hip/hip_runtime.h>

// RoI bilinear crop-and-resize (TF2 half-pixel-center resize semantics).
// image: (1, 128, 128, 1024) f32, rois: (256, 4) f32 [x, y, w, h]
// out:   (1, 256, 14, 14, 1024) f32
//
// One block per output pixel (n, yj, xj); 256 threads x float4 = 1024 channels.

#define H_ 128
#define W_ 128
#define C_ 1024
#define POOL_ 14
#define NROI_ 256

__global__ __launch_bounds__(256) void roi_pool_kernel(
    const float* __restrict__ feat,   // (H, W, C)
    const float* __restrict__ rois,   // (N, 4)
    float* __restrict__ out)          // (N, 14, 14, C)
{
    const int blk = blockIdx.x;               // n*196 + yj*14 + xj
    const int xj = blk % POOL_;
    const int yj = (blk / POOL_) % POOL_;
    const int n  = blk / (POOL_ * POOL_);

    // Per-RoI geometry (redundant per-thread; ~40 flops, negligible).
    const float x = rois[n * 4 + 0];
    const float y = rois[n * 4 + 1];
    const float w = rois[n * 4 + 2];
    const float h = rois[n * 4 + 3];

    // jnp.round == round-half-to-even == rintf
    const int r  = (int)rintf((x - w * 0.5f) / 16.0f);
    const int c  = (int)rintf((y - h * 0.5f) / 16.0f);
    const int wf = max((int)rintf(w / 16.0f), 1);
    const int hf = max((int)rintf(h / 16.0f), 1);

    // y axis (rows): start=c, size=hf, limit=H
    const float scy  = (float)hf / (float)POOL_;
    const float srcy = ((float)yj + 0.5f) * scy - 0.5f;
    const float fly  = floorf(srcy);
    const float ty   = srcy - fly;                 // unclamped lerp weight
    const float hiy  = (float)(hf - 1);
    int y0 = (int)fminf(fmaxf(fly, 0.0f), hiy) + c;
    int y1 = (int)fminf(fmaxf(fly + 1.0f, 0.0f), hiy) + c;
    y0 = min(max(y0, 0), H_ - 1);
    y1 = min(max(y1, 0), H_ - 1);

    // x axis (cols): start=r, size=wf, limit=W
    const float scx  = (float)wf / (float)POOL_;
    const float srcx = ((float)xj + 0.5f) * scx - 0.5f;
    const float flx  = floorf(srcx);
    const float tx   = srcx - flx;
    const float hix  = (float)(wf - 1);
    int x0 = (int)fminf(fmaxf(flx, 0.0f), hix) + r;
    int x1 = (int)fminf(fmaxf(flx + 1.0f, 0.0f), hix) + r;
    x0 = min(max(x0, 0), W_ - 1);
    x1 = min(max(x1, 0), W_ - 1);

    const float4* __restrict__ p00 =
        (const float4*)(feat + ((size_t)y0 * W_ + x0) * C_);
    const float4* __restrict__ p01 =
        (const float4*)(feat + ((size_t)y0 * W_ + x1) * C_);
    const float4* __restrict__ p10 =
        (const float4*)(feat + ((size_t)y1 * W_ + x0) * C_);
    const float4* __restrict__ p11 =
        (const float4*)(feat + ((size_t)y1 * W_ + x1) * C_);
    float4* __restrict__ po = (float4*)(out + (size_t)blk * C_);

    const int tid = threadIdx.x;   // 0..255, C/4 = 256 float4 per pixel

    const float4 v00 = p00[tid];
    const float4 v01 = p01[tid];
    const float4 v10 = p10[tid];
    const float4 v11 = p11[tid];

    const float omty = 1.0f - ty;
    const float omtx = 1.0f - tx;

    // Match reference order: (v00*(1-ty) + v10*ty)*(1-tx) + (v01*(1-ty) + v11*ty)*tx
    float4 o;
    o.x = (v00.x * omty + v10.x * ty) * omtx + (v01.x * omty + v11.x * ty) * tx;
    o.y = (v00.y * omty + v10.y * ty) * omtx + (v01.y * omty + v11.y * ty) * tx;
    o.z = (v00.z * omty + v10.z * ty) * omtx + (v01.z * omty + v11.z * ty) * tx;
    o.w = (v00.w * omty + v10.w * ty) * omtx + (v01.w * omty + v11.w * ty) * tx;

    po[tid] = o;
}

extern "C" void kernel_launch(void* const* d_in, const int* in_sizes, int n_in,
                              void* d_out, int out_size, void* d_ws, size_t ws_size,
                              hipStream_t stream) {
    const float* feat = (const float*)d_in[0];   // (1,128,128,1024) f32
    const float* rois = (const float*)d_in[1];   // (256,4) f32
    float* out = (float*)d_out;                  // (1,256,14,14,1024) f32

    const int nblocks = NROI_ * POOL_ * POOL_;   // 50176
    roi_pool_kernel<<<nblocks, 256, 0, stream>>>(feat, rois, out);
}

// Round 3
// 85.559 us; speedup vs baseline: 1.6376x; 1.6376x over previous
//
#include <hip/hip_runtime.h>

// RoI bilinear crop-and-resize (TF2 half-pixel-center resize semantics).
// image: (1, 128, 128, 1024) f32, rois: (256, 4) f32 [x, y, w, h]
// out:   (1, 256, 14, 14, 1024) f32
//
// One block per output pixel (n, yj, xj); 256 threads x float4 = 1024 channels.
// R3: non-temporal output stores via native ext_vector_type (keep 64MB image
//     resident in L3 instead of letting the 205MB write stream evict it)
//     + XCD swizzle so each RoI's ~1.8MB source footprint stays in one L2.

#define H_ 128
#define W_ 128
#define C_ 1024
#define POOL_ 14
#define NROI_ 256
#define NBLK_ (NROI_ * POOL_ * POOL_)   // 50176, divisible by 8
#define NXCD_ 8

typedef float f32x4 __attribute__((ext_vector_type(4)));

__global__ __launch_bounds__(256) void roi_pool_kernel(
    const float* __restrict__ feat,   // (H, W, C)
    const float* __restrict__ rois,   // (N, 4)
    float* __restrict__ out)          // (N, 14, 14, C)
{
    // Bijective XCD swizzle: hardware assigns blockIdx.x -> XCD (blockIdx.x % 8);
    // remap so XCD k processes contiguous work ids [k*6272, (k+1)*6272)
    // == RoIs [k*32, (k+1)*32) -> per-RoI footprint resident in one L2.
    const int bid = blockIdx.x;
    const int blk = (bid % NXCD_) * (NBLK_ / NXCD_) + bid / NXCD_;

    const int xj = blk % POOL_;
    const int yj = (blk / POOL_) % POOL_;
    const int n  = blk / (POOL_ * POOL_);

    // Per-RoI geometry (redundant per-thread; ~40 flops, negligible).
    const float x = rois[n * 4 + 0];
    const float y = rois[n * 4 + 1];
    const float w = rois[n * 4 + 2];
    const float h = rois[n * 4 + 3];

    // jnp.round == round-half-to-even == rintf
    const int r  = (int)rintf((x - w * 0.5f) / 16.0f);
    const int c  = (int)rintf((y - h * 0.5f) / 16.0f);
    const int wf = max((int)rintf(w / 16.0f), 1);
    const int hf = max((int)rintf(h / 16.0f), 1);

    // y axis (rows): start=c, size=hf, limit=H
    const float scy  = (float)hf / (float)POOL_;
    const float srcy = ((float)yj + 0.5f) * scy - 0.5f;
    const float fly  = floorf(srcy);
    const float ty   = srcy - fly;                 // unclamped lerp weight
    const float hiy  = (float)(hf - 1);
    int y0 = (int)fminf(fmaxf(fly, 0.0f), hiy) + c;
    int y1 = (int)fminf(fmaxf(fly + 1.0f, 0.0f), hiy) + c;
    y0 = min(max(y0, 0), H_ - 1);
    y1 = min(max(y1, 0), H_ - 1);

    // x axis (cols): start=r, size=wf, limit=W
    const float scx  = (float)wf / (float)POOL_;
    const float srcx = ((float)xj + 0.5f) * scx - 0.5f;
    const float flx  = floorf(srcx);
    const float tx   = srcx - flx;
    const float hix  = (float)(wf - 1);
    int x0 = (int)fminf(fmaxf(flx, 0.0f), hix) + r;
    int x1 = (int)fminf(fmaxf(flx + 1.0f, 0.0f), hix) + r;
    x0 = min(max(x0, 0), W_ - 1);
    x1 = min(max(x1, 0), W_ - 1);

    const f32x4* __restrict__ p00 =
        (const f32x4*)(feat + ((size_t)y0 * W_ + x0) * C_);
    const f32x4* __restrict__ p01 =
        (const f32x4*)(feat + ((size_t)y0 * W_ + x1) * C_);
    const f32x4* __restrict__ p10 =
        (const f32x4*)(feat + ((size_t)y1 * W_ + x0) * C_);
    const f32x4* __restrict__ p11 =
        (const f32x4*)(feat + ((size_t)y1 * W_ + x1) * C_);
    f32x4* __restrict__ po = (f32x4*)(out + (size_t)blk * C_);

    const int tid = threadIdx.x;   // 0..255, C/4 = 256 float4 per pixel

    const f32x4 v00 = p00[tid];
    const f32x4 v01 = p01[tid];
    const f32x4 v10 = p10[tid];
    const f32x4 v11 = p11[tid];

    const float omty = 1.0f - ty;
    const float omtx = 1.0f - tx;

    // Match reference order: (v00*(1-ty) + v10*ty)*(1-tx) + (v01*(1-ty) + v11*ty)*tx
    f32x4 o;
    o = (v00 * omty + v10 * ty) * omtx + (v01 * omty + v11 * ty) * tx;

    // Non-temporal: stream the output past L2/L3 so the image stays cached.
    __builtin_nontemporal_store(o, &po[tid]);
}

extern "C" void kernel_launch(void* const* d_in, const int* in_sizes, int n_in,
                              void* d_out, int out_size, void* d_ws, size_t ws_size,
                              hipStream_t stream) {
    const float* feat = (const float*)d_in[0];   // (1,128,128,1024) f32
    const float* rois = (const float*)d_in[1];   // (256,4) f32
    float* out = (float*)d_out;                  // (1,256,14,14,1024) f32

    roi_pool_kernel<<<NBLK_, 256, 0, stream>>>(feat, rois, out);
}